// Round 1
// baseline (5880.603 us; speedup 1.0000x reference)
//
#include <hip/hip_runtime.h>
#include <math.h>

#define B_  2
#define S_  2048
#define D_  1024
#define H_  16
#define L_  8
#define DH_ 64

// ---------------------------------------------------------------------------
// Generic fp32 GEMM: C[m,n] = sum_k A[m,k] * W[n,k] + bias[n]
// A: [M,K] row-major, W: [N,K] row-major (i.e. C = A @ W.T + bias)
// mode 0: out[m*N + n]                (row-major [M,N])
// mode 1: out[((b*H + h)*S + s)*DH+d] (head-split [B,H,S,DH], m=b*S+s, n=h*DH+d)
// Tiles: 64x64, BK=16, 256 threads, 4x4 per-thread microtile.
// ---------------------------------------------------------------------------
__global__ __launch_bounds__(256) void gemm_tn(const float* __restrict__ A,
                                               const float* __restrict__ W,
                                               const float* __restrict__ bias,
                                               float* __restrict__ out,
                                               int M, int N, int K, int mode)
{
    // +4 pad keeps rows 272B apart: 16B-aligned for float4 LDS reads,
    // bank pattern (4k + m) % 32 -> conflict-free reads, 2-way on writes (free).
    __shared__ float As[16][68];
    __shared__ float Ws[16][68];

    const int tid = threadIdx.x;
    const int tx = tid & 15;   // n-subtile (4 cols each)
    const int ty = tid >> 4;   // m-subtile (4 rows each)
    const int bm = blockIdx.y * 64;
    const int bn = blockIdx.x * 64;

    const int lc = tid & 15;   // k within tile
    const int lr = tid >> 4;   // row base (step 16)

    const float* Ap = A + (long)(bm + lr) * K + lc;
    const float* Wp = W + (long)(bn + lr) * K + lc;

    float acc[4][4] = {};

    for (int k0 = 0; k0 < K; k0 += 16) {
#pragma unroll
        for (int i = 0; i < 4; i++) {
            As[lc][lr + 16 * i] = Ap[(long)(16 * i) * K + k0];
            Ws[lc][lr + 16 * i] = Wp[(long)(16 * i) * K + k0];
        }
        __syncthreads();
#pragma unroll
        for (int kk = 0; kk < 16; kk++) {
            float4 a = *(const float4*)&As[kk][ty * 4];
            float4 w = *(const float4*)&Ws[kk][tx * 4];
            acc[0][0] += a.x * w.x; acc[0][1] += a.x * w.y; acc[0][2] += a.x * w.z; acc[0][3] += a.x * w.w;
            acc[1][0] += a.y * w.x; acc[1][1] += a.y * w.y; acc[1][2] += a.y * w.z; acc[1][3] += a.y * w.w;
            acc[2][0] += a.z * w.x; acc[2][1] += a.z * w.y; acc[2][2] += a.z * w.z; acc[2][3] += a.z * w.w;
            acc[3][0] += a.w * w.x; acc[3][1] += a.w * w.y; acc[3][2] += a.w * w.z; acc[3][3] += a.w * w.w;
        }
        __syncthreads();
    }

#pragma unroll
    for (int i = 0; i < 4; i++) {
        const int m = bm + ty * 4 + i;
#pragma unroll
        for (int j = 0; j < 4; j++) {
            const int n = bn + tx * 4 + j;
            const float v = acc[i][j] + bias[n];
            if (mode == 0) {
                out[(long)m * N + n] = v;
            } else {
                const int b = m / S_, s = m % S_;
                const int h = n / DH_, d = n % DH_;
                out[(long)(((b * H_ + h) * S_ + s)) * DH_ + d] = v;
            }
        }
    }
}

// ---------------------------------------------------------------------------
// Attention: one wave (64 lanes) per query row (b,h,s).
// qkv: [B*S, 3*D] row-major (q at col 0, k at D, v at 2D; head h at h*DH).
// Online softmax over causal keys t<=s (64-key chunks, lane j scores key
// chunk*64+j) then L=8 depth-memory slots, all one joint softmax.
// ctx accumulation: lane = output dim; per-key p broadcast via __shfl.
// Output ctx: [B*S, D] row-major with col h*DH+d (ready for Wo GEMM).
// ---------------------------------------------------------------------------
__global__ __launch_bounds__(256) void attn_kernel(const float* __restrict__ qkv,
                                                   const float* __restrict__ pk,
                                                   const float* __restrict__ pv,
                                                   float* __restrict__ ctx)
{
    const int wid  = (blockIdx.x * blockDim.x + threadIdx.x) >> 6; // global wave
    const int lane = threadIdx.x & 63;
    const int s  = wid % S_;
    const int bh = wid / S_;          // b*H + h
    const int b  = bh / H_;
    const int h  = bh % H_;

    // q row into registers (16 float4 = 64 floats)
    const float4* qp = (const float4*)(qkv + (long)(b * S_ + s) * (3 * D_) + h * DH_);
    float4 qv[16];
#pragma unroll
    for (int i = 0; i < 16; i++) qv[i] = qp[i];

    const float scale = 0.125f; // 1/sqrt(64)
    float m_run = -INFINITY;
    float l_run = 0.0f;
    float acc   = 0.0f;

    const int nChunks = (s >> 6) + 1;
    for (int c = 0; c < nChunks; c++) {
        const int t = (c << 6) + lane;
        float sc = -INFINITY;
        if (t <= s) {
            const float4* kp = (const float4*)(qkv + (long)(b * S_ + t) * (3 * D_) + D_ + h * DH_);
            float d = 0.0f;
#pragma unroll
            for (int i = 0; i < 16; i++) {
                float4 kk = kp[i];
                d += kk.x * qv[i].x + kk.y * qv[i].y + kk.z * qv[i].z + kk.w * qv[i].w;
            }
            sc = d * scale;
        }
        // wave max
        float mx = sc;
#pragma unroll
        for (int off = 32; off > 0; off >>= 1)
            mx = fmaxf(mx, __shfl_xor(mx, off));
        const float mnew  = fmaxf(m_run, mx);
        const float alpha = __expf(m_run - mnew);
        const float p     = __expf(sc - mnew); // 0 for masked lanes
        float ps = p;
#pragma unroll
        for (int off = 32; off > 0; off >>= 1)
            ps += __shfl_xor(ps, off);
        l_run = l_run * alpha + ps;
        acc  *= alpha;
        m_run = mnew;

        const int tmax = (s - (c << 6) + 1 < 64) ? (s - (c << 6) + 1) : 64;
        const float* vbase = qkv + (long)(b * S_ + (c << 6)) * (3 * D_) + 2 * D_ + h * DH_ + lane;
        for (int jj = 0; jj < tmax; jj++) {
            const float pj = __shfl(p, jj);
            acc += pj * vbase[(long)jj * (3 * D_)];
        }
    }

    // depth-memory slots (L=8), continuing the same online softmax
    {
        float sc = -INFINITY;
        const float* pkrow = pk + (long)((bh * S_ + s) * L_) * DH_;
        if (lane < L_) {
            const float4* kp = (const float4*)(pkrow + lane * DH_);
            float d = 0.0f;
#pragma unroll
            for (int i = 0; i < 16; i++) {
                float4 kk = kp[i];
                d += kk.x * qv[i].x + kk.y * qv[i].y + kk.z * qv[i].z + kk.w * qv[i].w;
            }
            sc = d * scale;
        }
        float mx = sc;
#pragma unroll
        for (int off = 32; off > 0; off >>= 1)
            mx = fmaxf(mx, __shfl_xor(mx, off));
        const float mnew  = fmaxf(m_run, mx);
        const float alpha = __expf(m_run - mnew);
        const float p     = __expf(sc - mnew);
        float ps = p;
#pragma unroll
        for (int off = 32; off > 0; off >>= 1)
            ps += __shfl_xor(ps, off);
        l_run = l_run * alpha + ps;
        acc  *= alpha;
        m_run = mnew;

        const float* pvrow = pv + (long)((bh * S_ + s) * L_) * DH_ + lane;
#pragma unroll
        for (int jj = 0; jj < L_; jj++) {
            const float pj = __shfl(p, jj);
            acc += pj * pvrow[jj * DH_];
        }
    }

    ctx[(long)(b * S_ + s) * D_ + h * DH_ + lane] = acc / l_run;
}

// ---------------------------------------------------------------------------
extern "C" void kernel_launch(void* const* d_in, const int* in_sizes, int n_in,
                              void* d_out, int out_size, void* d_ws, size_t ws_size,
                              hipStream_t stream)
{
    const float* x    = (const float*)d_in[0];
    const float* pk   = (const float*)d_in[1];
    const float* pv   = (const float*)d_in[2];
    const float* Wqkv = (const float*)d_in[3];
    const float* bqkv = (const float*)d_in[4];
    const float* Wk   = (const float*)d_in[5];
    const float* bk   = (const float*)d_in[6];
    const float* Wv   = (const float*)d_in[7];
    const float* bv   = (const float*)d_in[8];
    const float* Wo   = (const float*)d_in[9];
    const float* bo   = (const float*)d_in[10];

    float* out   = (float*)d_out;                      // [B,S,D]
    float* k_col = out + (long)B_ * S_ * D_;           // [B,H,S,DH]
    float* v_col = k_col + (long)B_ * H_ * S_ * DH_;   // [B,H,S,DH]

    float* ws_qkv = (float*)d_ws;                              // [B*S, 3D] = 50.3 MB
    float* ws_ctx = ws_qkv + (long)B_ * S_ * 3 * D_;           // [B*S, D]  = 16.8 MB

    const int M = B_ * S_;   // 4096
    const int K = D_;        // 1024

    dim3 blk(256);

    // 1) qkv = x @ Wqkv.T + bqkv  -> ws_qkv [M, 3D]
    gemm_tn<<<dim3(3 * D_ / 64, M / 64), blk, 0, stream>>>(x, Wqkv, bqkv, ws_qkv, M, 3 * D_, K, 0);
    // 2) k_col = split_heads(x @ Wk.T + bk) -> [B,H,S,DH]
    gemm_tn<<<dim3(D_ / 64, M / 64), blk, 0, stream>>>(x, Wk, bk, k_col, M, D_, K, 1);
    // 3) v_col = split_heads(x @ Wv.T + bv) -> [B,H,S,DH]
    gemm_tn<<<dim3(D_ / 64, M / 64), blk, 0, stream>>>(x, Wv, bv, v_col, M, D_, K, 1);
    // 4) attention -> ws_ctx [M, D]
    attn_kernel<<<dim3(B_ * H_ * S_ / 4), blk, 0, stream>>>(ws_qkv, pk, pv, ws_ctx);
    // 5) out = ctx @ Wo.T + bo -> [M, D]
    gemm_tn<<<dim3(D_ / 64, M / 64), blk, 0, stream>>>(ws_ctx, Wo, bo, out, M, D_, K, 0);
}

// Round 2
// 1309.078 us; speedup vs baseline: 4.4922x; 4.4922x over previous
//
#include <hip/hip_runtime.h>
#include <math.h>

#define B_  2
#define S_  2048
#define D_  1024
#define H_  16
#define L_  8
#define DH_ 64

typedef __attribute__((ext_vector_type(8))) short   short8;  // 8 bf16 (4 VGPRs)
typedef __attribute__((ext_vector_type(4))) float   f32x4;   // MFMA C/D frag
typedef __attribute__((ext_vector_type(8))) unsigned short us8;

static __device__ __forceinline__ unsigned short f2bf(float f) {
    union { float f; unsigned int u; } x; x.f = f;
    unsigned int r = x.u + 0x7FFFu + ((x.u >> 16) & 1u);   // RNE
    return (unsigned short)(r >> 16);
}

// ---------------------------------------------------------------------------
// fp32 GEMM (unchanged from round 1): C = A @ W.T + bias
// mode 0: row-major [M,N]; mode 1: head-split [B,H,S,DH]
// ---------------------------------------------------------------------------
__global__ __launch_bounds__(256) void gemm_tn(const float* __restrict__ A,
                                               const float* __restrict__ W,
                                               const float* __restrict__ bias,
                                               float* __restrict__ out,
                                               int M, int N, int K, int mode)
{
    __shared__ float As[16][68];
    __shared__ float Ws[16][68];

    const int tid = threadIdx.x;
    const int tx = tid & 15;
    const int ty = tid >> 4;
    const int bm = blockIdx.y * 64;
    const int bn = blockIdx.x * 64;

    const int lc = tid & 15;
    const int lr = tid >> 4;

    const float* Ap = A + (long)(bm + lr) * K + lc;
    const float* Wp = W + (long)(bn + lr) * K + lc;

    float acc[4][4] = {};

    for (int k0 = 0; k0 < K; k0 += 16) {
#pragma unroll
        for (int i = 0; i < 4; i++) {
            As[lc][lr + 16 * i] = Ap[(long)(16 * i) * K + k0];
            Ws[lc][lr + 16 * i] = Wp[(long)(16 * i) * K + k0];
        }
        __syncthreads();
#pragma unroll
        for (int kk = 0; kk < 16; kk++) {
            float4 a = *(const float4*)&As[kk][ty * 4];
            float4 w = *(const float4*)&Ws[kk][tx * 4];
            acc[0][0] += a.x * w.x; acc[0][1] += a.x * w.y; acc[0][2] += a.x * w.z; acc[0][3] += a.x * w.w;
            acc[1][0] += a.y * w.x; acc[1][1] += a.y * w.y; acc[1][2] += a.y * w.z; acc[1][3] += a.y * w.w;
            acc[2][0] += a.z * w.x; acc[2][1] += a.z * w.y; acc[2][2] += a.z * w.z; acc[2][3] += a.z * w.w;
            acc[3][0] += a.w * w.x; acc[3][1] += a.w * w.y; acc[3][2] += a.w * w.z; acc[3][3] += a.w * w.w;
        }
        __syncthreads();
    }

#pragma unroll
    for (int i = 0; i < 4; i++) {
        const int m = bm + ty * 4 + i;
#pragma unroll
        for (int j = 0; j < 4; j++) {
            const int n = bn + tx * 4 + j;
            const float v = acc[i][j] + bias[n];
            if (mode == 0) {
                out[(long)m * N + n] = v;
            } else {
                const int b = m / S_, s = m % S_;
                const int h = n / DH_, d = n % DH_;
                out[(long)(((b * H_ + h) * S_ + s)) * DH_ + d] = v;
            }
        }
    }
}

// ---------------------------------------------------------------------------
// Pre-pass: K -> bf16 [B,H,S,DH]; V -> bf16 transposed [B,H,DH,S].
// One block per (b,h, 64-row s-tile).
// ---------------------------------------------------------------------------
__global__ __launch_bounds__(256) void prepass(const float* __restrict__ qkv,
                                               unsigned short* __restrict__ Kb,
                                               unsigned short* __restrict__ Vtb)
{
    __shared__ float tile[64][65];
    const int bi = blockIdx.x;              // B*H*(S/64) = 1024
    const int st = bi & 31;
    const int bh = bi >> 5;
    const int b = bh >> 4, h = bh & 15;
    const int t = threadIdx.x;
    const int s_l = t >> 2;
    const int dch = (t & 3) * 16;

    const float* src = qkv + ((long)(b * S_ + st * 64 + s_l)) * (3 * D_) + h * DH_ + dch;

    // K: straight bf16 convert, coalesced
    {
        const float4* p4 = (const float4*)(src + D_);
        us8 o0, o1;
#pragma unroll
        for (int i = 0; i < 2; i++) {
            float4 v = p4[i];
            o0[4*i+0]=f2bf(v.x); o0[4*i+1]=f2bf(v.y); o0[4*i+2]=f2bf(v.z); o0[4*i+3]=f2bf(v.w);
        }
#pragma unroll
        for (int i = 0; i < 2; i++) {
            float4 v = p4[2+i];
            o1[4*i+0]=f2bf(v.x); o1[4*i+1]=f2bf(v.y); o1[4*i+2]=f2bf(v.z); o1[4*i+3]=f2bf(v.w);
        }
        us8* dst = (us8*)(Kb + ((long)bh * S_ + st * 64 + s_l) * DH_ + dch);
        dst[0] = o0; dst[1] = o1;
    }
    // V: stage fp32 tile, transpose, bf16 out
    {
        const float4* p4 = (const float4*)(src + 2 * D_);
#pragma unroll
        for (int i = 0; i < 4; i++) {
            float4 v = p4[i];
            tile[s_l][dch + 4*i + 0] = v.x;
            tile[s_l][dch + 4*i + 1] = v.y;
            tile[s_l][dch + 4*i + 2] = v.z;
            tile[s_l][dch + 4*i + 3] = v.w;
        }
    }
    __syncthreads();
    {
        const int d_l = t >> 2;
        const int sch = (t & 3) * 16;
        us8 o0, o1;
#pragma unroll
        for (int i = 0; i < 8; i++) o0[i] = f2bf(tile[sch + i][d_l]);
#pragma unroll
        for (int i = 0; i < 8; i++) o1[i] = f2bf(tile[sch + 8 + i][d_l]);
        us8* dst = (us8*)(Vtb + ((long)bh * DH_ + d_l) * S_ + st * 64 + sch);
        dst[0] = o0; dst[1] = o1;
    }
}

// ---------------------------------------------------------------------------
// MFMA flash attention with depth-memory slots folded in as the initial
// online-softmax state. Block = 64 Q rows (4 waves x 16 rows), K-tiles of 64.
// 16x16x32 bf16 MFMA; C/D layout: row=(lane>>4)*4+reg, col=lane&15;
// A layout: m=lane&15, k=(lane>>4)*8+j.
// ---------------------------------------------------------------------------
__global__ __launch_bounds__(256) void attn_mfma(
    const float* __restrict__ qkv,
    const unsigned short* __restrict__ Kb,
    const unsigned short* __restrict__ Vtb,
    const float* __restrict__ pk,
    const float* __restrict__ pv,
    float* __restrict__ ctx)
{
    __shared__ float msc[4][16][8];
    // pad to 72 bf16/row: rows 144B apart -> 16B-aligned b128 reads
    __shared__ __align__(16) unsigned short Pl[4][16][72];

    const int bi = blockIdx.x;
    const int qt = 31 - (bi & 31);          // long blocks first
    const int bh = bi >> 5;
    const int b = bh >> 4, h = bh & 15;
    const int w = threadIdx.x >> 6;
    const int lane = threadIdx.x & 63;
    const int g = lane >> 4;
    const int c = lane & 15;
    const int qrow0 = qt * 64 + w * 16;
    const float scale = 0.125f;             // 1/sqrt(64)

    // Q A-frags, bf16, scale folded in
    short8 qa0, qa1;
    {
        const float* qp = qkv + ((long)(b * S_) + qrow0 + c) * (3 * D_) + h * DH_;
        const float4* p0 = (const float4*)(qp + g * 8);
        const float4* p1 = (const float4*)(qp + 32 + g * 8);
        float4 a0 = p0[0], a1 = p0[1], b0 = p1[0], b1 = p1[1];
        qa0[0]=(short)f2bf(a0.x*scale); qa0[1]=(short)f2bf(a0.y*scale);
        qa0[2]=(short)f2bf(a0.z*scale); qa0[3]=(short)f2bf(a0.w*scale);
        qa0[4]=(short)f2bf(a1.x*scale); qa0[5]=(short)f2bf(a1.y*scale);
        qa0[6]=(short)f2bf(a1.z*scale); qa0[7]=(short)f2bf(a1.w*scale);
        qa1[0]=(short)f2bf(b0.x*scale); qa1[1]=(short)f2bf(b0.y*scale);
        qa1[2]=(short)f2bf(b0.z*scale); qa1[3]=(short)f2bf(b0.w*scale);
        qa1[4]=(short)f2bf(b1.x*scale); qa1[5]=(short)f2bf(b1.y*scale);
        qa1[6]=(short)f2bf(b1.z*scale); qa1[7]=(short)f2bf(b1.w*scale);
    }

    // ---- depth-memory slots as initial softmax state (fp32 q/pk/pv) ----
    {
        const int r0 = lane >> 3, l0 = lane & 7;
#pragma unroll
        for (int pass = 0; pass < 2; pass++) {
            const int r = r0 + pass * 8;
            const float4* q4 = (const float4*)(qkv + ((long)(b * S_) + qrow0 + r) * (3 * D_) + h * DH_);
            const float4* k4 = (const float4*)(pk + (((long)bh * S_ + qrow0 + r) * L_ + l0) * DH_);
            float d = 0.0f;
#pragma unroll
            for (int i = 0; i < 16; i++) {
                float4 a = q4[i], kk = k4[i];
                d += a.x*kk.x + a.y*kk.y + a.z*kk.z + a.w*kk.w;
            }
            msc[w][r][l0] = d * scale;
        }
    }
    __syncthreads();

    float m[4], lsum[4];
    f32x4 O[4];
#pragma unroll
    for (int f = 0; f < 4; f++) { O[f][0]=0.f; O[f][1]=0.f; O[f][2]=0.f; O[f][3]=0.f; }

#pragma unroll
    for (int reg = 0; reg < 4; reg++) {
        const int r = g * 4 + reg;
        float s8[8];
#pragma unroll
        for (int l = 0; l < 8; l++) s8[l] = msc[w][r][l];
        float mx = s8[0];
#pragma unroll
        for (int l = 1; l < 8; l++) mx = fmaxf(mx, s8[l]);
        float p8[8]; float ls = 0.0f;
#pragma unroll
        for (int l = 0; l < 8; l++) { p8[l] = __expf(s8[l] - mx); ls += p8[l]; }
        m[reg] = mx; lsum[reg] = ls;
        const float* pvr = pv + ((long)bh * S_ + qrow0 + r) * (L_ * DH_) + c;
#pragma unroll
        for (int l = 0; l < 8; l++) {
#pragma unroll
            for (int f = 0; f < 4; f++)
                O[f][reg] += p8[l] * pvr[l * DH_ + f * 16];
        }
    }

    const unsigned short* Kh = Kb + (long)bh * S_ * DH_;
    const unsigned short* Vh = Vtb + (long)bh * DH_ * S_;
    const int tEnd = qt * 64;

    for (int t0 = 0; t0 <= tEnd; t0 += 64) {
        // ---- QK^T: 4 col-tiles x 2 k-steps ----
        f32x4 sc[4];
#pragma unroll
        for (int nt = 0; nt < 4; nt++) {
            const unsigned short* kp = Kh + ((long)(t0 + nt * 16 + c)) * DH_ + g * 8;
            short8 kb0 = *(const short8*)kp;
            short8 kb1 = *(const short8*)(kp + 32);
            f32x4 a; a[0]=0.f; a[1]=0.f; a[2]=0.f; a[3]=0.f;
            a = __builtin_amdgcn_mfma_f32_16x16x32_bf16(qa0, kb0, a, 0, 0, 0);
            a = __builtin_amdgcn_mfma_f32_16x16x32_bf16(qa1, kb1, a, 0, 0, 0);
            sc[nt] = a;
        }
        if (t0 == tEnd) {                   // diagonal tile: causal mask
#pragma unroll
            for (int nt = 0; nt < 4; nt++)
#pragma unroll
                for (int reg = 0; reg < 4; reg++)
                    sc[nt][reg] = (nt * 16 + c > w * 16 + g * 4 + reg) ? -INFINITY : sc[nt][reg];
        }
        // ---- online softmax ----
        float al[4];
#pragma unroll
        for (int reg = 0; reg < 4; reg++) {
            float mx = fmaxf(fmaxf(sc[0][reg], sc[1][reg]), fmaxf(sc[2][reg], sc[3][reg]));
            mx = fmaxf(mx, __shfl_xor(mx, 1));
            mx = fmaxf(mx, __shfl_xor(mx, 2));
            mx = fmaxf(mx, __shfl_xor(mx, 4));
            mx = fmaxf(mx, __shfl_xor(mx, 8));
            const float mn = fmaxf(m[reg], mx);
            const float a  = __expf(m[reg] - mn);
            m[reg] = mn; al[reg] = a;
            float ps = 0.0f;
#pragma unroll
            for (int nt = 0; nt < 4; nt++) {
                float p = __expf(sc[nt][reg] - mn);
                sc[nt][reg] = p; ps += p;
            }
            ps += __shfl_xor(ps, 1); ps += __shfl_xor(ps, 2);
            ps += __shfl_xor(ps, 4); ps += __shfl_xor(ps, 8);
            lsum[reg] = lsum[reg] * a + ps;
        }
#pragma unroll
        for (int f = 0; f < 4; f++)
#pragma unroll
            for (int reg = 0; reg < 4; reg++)
                O[f][reg] *= al[reg];
        // ---- P: C-layout -> LDS -> A-layout ----
#pragma unroll
        for (int nt = 0; nt < 4; nt++)
#pragma unroll
            for (int reg = 0; reg < 4; reg++)
                Pl[w][g * 4 + reg][nt * 16 + c] = f2bf(sc[nt][reg]);
        __syncthreads();
        short8 pa0 = *(const short8*)&Pl[w][c][g * 8];
        short8 pa1 = *(const short8*)&Pl[w][c][32 + g * 8];
        // ---- PV ----
#pragma unroll
        for (int nt = 0; nt < 4; nt++) {
            const unsigned short* vp = Vh + ((long)(nt * 16 + c)) * S_ + t0 + g * 8;
            short8 vb0 = *(const short8*)vp;
            short8 vb1 = *(const short8*)(vp + 32);
            O[nt] = __builtin_amdgcn_mfma_f32_16x16x32_bf16(pa0, vb0, O[nt], 0, 0, 0);
            O[nt] = __builtin_amdgcn_mfma_f32_16x16x32_bf16(pa1, vb1, O[nt], 0, 0, 0);
        }
    }

    // ---- epilogue ----
#pragma unroll
    for (int reg = 0; reg < 4; reg++) {
        const float rl = 1.0f / lsum[reg];
        float* op = ctx + ((long)(b * S_) + qrow0 + g * 4 + reg) * D_ + h * DH_ + c;
#pragma unroll
        for (int f = 0; f < 4; f++)
            op[f * 16] = O[f][reg] * rl;
    }
}

// ---------------------------------------------------------------------------
extern "C" void kernel_launch(void* const* d_in, const int* in_sizes, int n_in,
                              void* d_out, int out_size, void* d_ws, size_t ws_size,
                              hipStream_t stream)
{
    const float* x    = (const float*)d_in[0];
    const float* pk   = (const float*)d_in[1];
    const float* pv   = (const float*)d_in[2];
    const float* Wqkv = (const float*)d_in[3];
    const float* bqkv = (const float*)d_in[4];
    const float* Wk   = (const float*)d_in[5];
    const float* bk   = (const float*)d_in[6];
    const float* Wv   = (const float*)d_in[7];
    const float* bv   = (const float*)d_in[8];
    const float* Wo   = (const float*)d_in[9];
    const float* bo   = (const float*)d_in[10];

    float* out   = (float*)d_out;                      // [B,S,D]
    float* k_col = out + (long)B_ * S_ * D_;           // [B,H,S,DH]
    float* v_col = k_col + (long)B_ * H_ * S_ * DH_;   // [B,H,S,DH]

    const int M = B_ * S_;   // 4096
    const int K = D_;        // 1024

    float* ws_qkv = (float*)d_ws;                               // [M, 3D]
    float* ws_ctx = ws_qkv + (long)M * 3 * D_;                  // [M, D]
    unsigned short* Kb  = (unsigned short*)(ws_ctx + (long)M * D_); // [B,H,S,DH] bf16
    unsigned short* Vtb = Kb + (long)B_ * H_ * S_ * DH_;            // [B,H,DH,S] bf16

    dim3 blk(256);

    // 1) qkv = x @ Wqkv.T + bqkv
    gemm_tn<<<dim3(3 * D_ / 64, M / 64), blk, 0, stream>>>(x, Wqkv, bqkv, ws_qkv, M, 3 * D_, K, 0);
    // 2) bf16 K + transposed bf16 V
    prepass<<<dim3(B_ * H_ * (S_ / 64)), blk, 0, stream>>>(ws_qkv, Kb, Vtb);
    // 3) k_col / v_col (independent)
    gemm_tn<<<dim3(D_ / 64, M / 64), blk, 0, stream>>>(x, Wk, bk, k_col, M, D_, K, 1);
    gemm_tn<<<dim3(D_ / 64, M / 64), blk, 0, stream>>>(x, Wv, bv, v_col, M, D_, K, 1);
    // 4) attention
    attn_mfma<<<dim3(B_ * H_ * (S_ / 64)), blk, 0, stream>>>(ws_qkv, Kb, Vtb, pk, pv, ws_ctx);
    // 5) out = ctx @ Wo.T + bo
    gemm_tn<<<dim3(D_ / 64, M / 64), blk, 0, stream>>>(ws_ctx, Wo, bo, out, M, D_, K, 0);
}

// Round 3
// 723.191 us; speedup vs baseline: 8.1315x; 1.8101x over previous
//
#include <hip/hip_runtime.h>
#include <math.h>

#define B_  2
#define S_  2048
#define D_  1024
#define H_  16
#define L_  8
#define DH_ 64

typedef __attribute__((ext_vector_type(8))) short   short8;  // 8 bf16 (4 VGPRs)
typedef __attribute__((ext_vector_type(4))) float   f32x4;   // MFMA C/D frag
typedef __attribute__((ext_vector_type(8))) unsigned short us8;

static __device__ __forceinline__ unsigned short f2bf(float f) {
    union { float f; unsigned int u; } x; x.f = f;
    unsigned int r = x.u + 0x7FFFu + ((x.u >> 16) & 1u);   // RNE
    return (unsigned short)(r >> 16);
}
static __device__ __forceinline__ float bf2f(unsigned short u) {
    union { unsigned int u; float f; } x; x.u = ((unsigned int)u) << 16;
    return x.f;
}
static __device__ __forceinline__ void glds16(const void* g, void* l) {
    __builtin_amdgcn_global_load_lds(
        (const __attribute__((address_space(1))) void*)g,
        (__attribute__((address_space(3))) void*)l, 16, 0, 0);
}

// ---------------------------------------------------------------------------
// fp32 -> bf16 elementwise convert (n multiple of 8; grid = n/8/256)
// ---------------------------------------------------------------------------
__global__ __launch_bounds__(256) void cvt_bf16(const float* __restrict__ src,
                                                unsigned short* __restrict__ dst,
                                                long n)
{
    const long i = ((long)blockIdx.x * 256 + threadIdx.x) * 8;
    if (i >= n) return;
    const float4 v0 = *(const float4*)(src + i);
    const float4 v1 = *(const float4*)(src + i + 4);
    us8 o;
    o[0] = f2bf(v0.x); o[1] = f2bf(v0.y); o[2] = f2bf(v0.z); o[3] = f2bf(v0.w);
    o[4] = f2bf(v1.x); o[5] = f2bf(v1.y); o[6] = f2bf(v1.z); o[7] = f2bf(v1.w);
    *(us8*)(dst + i) = o;
}

// ---------------------------------------------------------------------------
// bf16 MFMA GEMM: C[m,n] = A[m,:] . Wt[n,:] + bias[n]   (both K-contiguous)
// 128x128 tile, BK=32, 4 waves (2x2 of 64x64), 16x16x32 bf16 MFMA.
// LDS chunk swizzle: physical slot i (16B chunks) holds logical
// (r = i>>2, kc = (i&3) ^ ((r>>1)&3)).  Staging thread t writes slot t
// (lane-contiguous, required by global_load_lds); fragment ds_read_b128 for
// lane (g,c) hits slot 4r + (g ^ ((c>>1)&3)) -> bank groups spread over all
// 8, max 2-way (free).
// mode 0: fp32 [M,N]; mode 1: fp32 head-split [B,H,S,DH]; mode 2: bf16 [M,N]
// ---------------------------------------------------------------------------
__global__ __launch_bounds__(256) void gemm_bf16(
    const unsigned short* __restrict__ A,   // [M,K] bf16
    const unsigned short* __restrict__ Wt,  // [N,K] bf16
    const float* __restrict__ bias,         // [N]
    void* __restrict__ out,
    int M, int N, int K, int mode)
{
    __shared__ __align__(16) unsigned short Asm[128 * 32];
    __shared__ __align__(16) unsigned short Bsm[128 * 32];

    const int t  = threadIdx.x;
    const int bm = blockIdx.y * 128;
    const int bn = blockIdx.x * 128;
    const int w = t >> 6, lane = t & 63;
    const int g = lane >> 4, c = lane & 15;
    const int wm = (w & 1) * 64, wn = (w >> 1) * 64;

    // staging: thread t -> slot t (issue 0) and slot 256+t (issue 1)
    const int r0  = t >> 2;                       // 0..63
    const int kc0 = (t & 3) ^ ((r0 >> 1) & 3);    // same for issue 1 (r1 = r0+64)
    const unsigned short* Ap0 = A  + (long)(bm + r0)      * K + kc0 * 8;
    const unsigned short* Ap1 = A  + (long)(bm + r0 + 64) * K + kc0 * 8;
    const unsigned short* Bp0 = Wt + (long)(bn + r0)      * K + kc0 * 8;
    const unsigned short* Bp1 = Wt + (long)(bn + r0 + 64) * K + kc0 * 8;
    unsigned short* AsD0 = Asm + t * 8;
    unsigned short* AsD1 = Asm + (256 + t) * 8;
    unsigned short* BsD0 = Bsm + t * 8;
    unsigned short* BsD1 = Bsm + (256 + t) * 8;

    // fragment LDS byte offsets
    const int xv = (c >> 1) & 3;
    int offA[4], offB[4];
#pragma unroll
    for (int i = 0; i < 4; i++) {
        offA[i] = (4 * (wm + i * 16 + c) + (g ^ xv)) * 16;
        offB[i] = (4 * (wn + i * 16 + c) + (g ^ xv)) * 16;
    }

    f32x4 acc[4][4];
#pragma unroll
    for (int i = 0; i < 4; i++)
#pragma unroll
        for (int j = 0; j < 4; j++) { acc[i][j][0]=0.f; acc[i][j][1]=0.f; acc[i][j][2]=0.f; acc[i][j][3]=0.f; }

    for (int k0 = 0; k0 < K; k0 += 32) {
        glds16(Ap0 + k0, AsD0);
        glds16(Ap1 + k0, AsD1);
        glds16(Bp0 + k0, BsD0);
        glds16(Bp1 + k0, BsD1);
        __syncthreads();                      // drains vmcnt -> LDS valid

        short8 af[4], bf[4];
#pragma unroll
        for (int i = 0; i < 4; i++) af[i] = *(const short8*)((const char*)Asm + offA[i]);
#pragma unroll
        for (int i = 0; i < 4; i++) bf[i] = *(const short8*)((const char*)Bsm + offB[i]);
#pragma unroll
        for (int mt = 0; mt < 4; mt++)
#pragma unroll
            for (int nt = 0; nt < 4; nt++)
                acc[mt][nt] = __builtin_amdgcn_mfma_f32_16x16x32_bf16(af[mt], bf[nt], acc[mt][nt], 0, 0, 0);
        __syncthreads();                      // protect LDS before next stage
    }

#pragma unroll
    for (int mt = 0; mt < 4; mt++) {
#pragma unroll
        for (int nt = 0; nt < 4; nt++) {
            const int col = bn + wn + nt * 16 + c;
            const float bv = bias[col];
            const int row0 = bm + wm + mt * 16 + g * 4;
#pragma unroll
            for (int reg = 0; reg < 4; reg++) {
                const float val = acc[mt][nt][reg] + bv;
                const int rr = row0 + reg;
                if (mode == 0) {
                    ((float*)out)[(long)rr * N + col] = val;
                } else if (mode == 1) {
                    const int b = rr >> 11, s = rr & 2047;
                    const int h = col >> 6, d = col & 63;
                    ((float*)out)[(((long)(b * H_ + h)) * S_ + s) * DH_ + d] = val;
                } else {
                    ((unsigned short*)out)[(long)rr * N + col] = f2bf(val);
                }
            }
        }
    }
}

// ---------------------------------------------------------------------------
// Pre-pass (bf16 in): K -> packed [B,H,S,DH]; V -> transposed [B,H,DH,S].
// ---------------------------------------------------------------------------
__global__ __launch_bounds__(256) void prepass(const unsigned short* __restrict__ qkvb,
                                               unsigned short* __restrict__ Kb,
                                               unsigned short* __restrict__ Vtb)
{
    __shared__ __align__(16) unsigned short tile[64][72];
    const int bi = blockIdx.x;              // B*H*(S/64) = 1024
    const int st = bi & 31;
    const int bh = bi >> 5;
    const int b = bh >> 4, h = bh & 15;
    const int t = threadIdx.x;
    const int s_l = t >> 2;
    const int ch = (t & 3) * 16;            // 16 bf16 per thread

    const unsigned short* src = qkvb + (long)(b * S_ + st * 64 + s_l) * (3 * D_) + h * DH_;

    // K: straight copy into packed layout
    {
        us8 k0 = *(const us8*)(src + D_ + ch);
        us8 k1 = *(const us8*)(src + D_ + ch + 8);
        us8* kd = (us8*)(Kb + ((long)bh * S_ + st * 64 + s_l) * DH_ + ch);
        kd[0] = k0; kd[1] = k1;
    }
    // V: stage tile, transpose
    {
        us8 v0 = *(const us8*)(src + 2 * D_ + ch);
        us8 v1 = *(const us8*)(src + 2 * D_ + ch + 8);
        *(us8*)&tile[s_l][ch] = v0;
        *(us8*)&tile[s_l][ch + 8] = v1;
    }
    __syncthreads();
    {
        const int d_l = t >> 2;
        const int sch = (t & 3) * 16;
        us8 o0, o1;
#pragma unroll
        for (int i = 0; i < 8; i++) o0[i] = tile[sch + i][d_l];
#pragma unroll
        for (int i = 0; i < 8; i++) o1[i] = tile[sch + 8 + i][d_l];
        us8* dst = (us8*)(Vtb + ((long)bh * DH_ + d_l) * S_ + st * 64 + sch);
        dst[0] = o0; dst[1] = o1;
    }
}

// ---------------------------------------------------------------------------
// MFMA flash attention (bf16 qkv in, bf16 ctx out). Depth-memory slots are
// the initial online-softmax state. Block = 64 Q rows (4 waves x 16 rows).
// ---------------------------------------------------------------------------
__global__ __launch_bounds__(256) void attn_mfma(
    const unsigned short* __restrict__ qkvb,
    const unsigned short* __restrict__ Kb,
    const unsigned short* __restrict__ Vtb,
    const float* __restrict__ pk,
    const float* __restrict__ pv,
    unsigned short* __restrict__ ctxb)
{
    __shared__ float msc[4][16][8];
    __shared__ __align__(16) unsigned short Pl[4][16][72];

    const int bi = blockIdx.x;
    const int qt = 31 - (bi & 31);          // long blocks first
    const int bh = bi >> 5;
    const int b = bh >> 4, h = bh & 15;
    const int w = threadIdx.x >> 6;
    const int lane = threadIdx.x & 63;
    const int g = lane >> 4;
    const int c = lane & 15;
    const int qrow0 = qt * 64 + w * 16;
    const float scale = 0.125f;             // 1/sqrt(64); exact pow2

    // Q A-frags straight from bf16 qkv (scale applied post-MFMA)
    const unsigned short* qp = qkvb + ((long)(b * S_) + qrow0 + c) * (3 * D_) + h * DH_;
    const short8 qa0 = *(const short8*)(qp + g * 8);
    const short8 qa1 = *(const short8*)(qp + 32 + g * 8);

    // ---- depth-memory scores (bf16 q x fp32 pk) ----
    {
        const int r0 = lane >> 3, l0 = lane & 7;
#pragma unroll
        for (int pass = 0; pass < 2; pass++) {
            const int r = r0 + pass * 8;
            const unsigned short* qr = qkvb + ((long)(b * S_) + qrow0 + r) * (3 * D_) + h * DH_;
            const float4* k4 = (const float4*)(pk + (((long)bh * S_ + qrow0 + r) * L_ + l0) * DH_);
            float d = 0.0f;
#pragma unroll
            for (int i = 0; i < 8; i++) {
                const us8 q8 = *(const us8*)(qr + i * 8);
                const float4 ka = k4[2 * i], kb2 = k4[2 * i + 1];
                d += bf2f(q8[0]) * ka.x  + bf2f(q8[1]) * ka.y
                   + bf2f(q8[2]) * ka.z  + bf2f(q8[3]) * ka.w
                   + bf2f(q8[4]) * kb2.x + bf2f(q8[5]) * kb2.y
                   + bf2f(q8[6]) * kb2.z + bf2f(q8[7]) * kb2.w;
            }
            msc[w][r][l0] = d * scale;
        }
    }
    __syncthreads();

    float m[4], lsum[4];
    f32x4 O[4];
#pragma unroll
    for (int f = 0; f < 4; f++) { O[f][0]=0.f; O[f][1]=0.f; O[f][2]=0.f; O[f][3]=0.f; }

#pragma unroll
    for (int reg = 0; reg < 4; reg++) {
        const int r = g * 4 + reg;
        float s8[8];
#pragma unroll
        for (int l = 0; l < 8; l++) s8[l] = msc[w][r][l];
        float mx = s8[0];
#pragma unroll
        for (int l = 1; l < 8; l++) mx = fmaxf(mx, s8[l]);
        float p8[8]; float ls = 0.0f;
#pragma unroll
        for (int l = 0; l < 8; l++) { p8[l] = __expf(s8[l] - mx); ls += p8[l]; }
        m[reg] = mx; lsum[reg] = ls;
        const float* pvr = pv + ((long)bh * S_ + qrow0 + r) * (L_ * DH_) + c;
#pragma unroll
        for (int l = 0; l < 8; l++) {
#pragma unroll
            for (int f = 0; f < 4; f++)
                O[f][reg] += p8[l] * pvr[l * DH_ + f * 16];
        }
    }

    const unsigned short* Kh = Kb + (long)bh * S_ * DH_;
    const unsigned short* Vh = Vtb + (long)bh * DH_ * S_;
    const int tEnd = qt * 64;

    for (int t0 = 0; t0 <= tEnd; t0 += 64) {
        // ---- QK^T ----
        f32x4 sc[4];
#pragma unroll
        for (int nt = 0; nt < 4; nt++) {
            const unsigned short* kp = Kh + ((long)(t0 + nt * 16 + c)) * DH_ + g * 8;
            short8 kb0 = *(const short8*)kp;
            short8 kb1 = *(const short8*)(kp + 32);
            f32x4 a; a[0]=0.f; a[1]=0.f; a[2]=0.f; a[3]=0.f;
            a = __builtin_amdgcn_mfma_f32_16x16x32_bf16(qa0, kb0, a, 0, 0, 0);
            a = __builtin_amdgcn_mfma_f32_16x16x32_bf16(qa1, kb1, a, 0, 0, 0);
#pragma unroll
            for (int reg = 0; reg < 4; reg++) a[reg] *= scale;
            sc[nt] = a;
        }
        if (t0 == tEnd) {                   // diagonal tile: causal mask
#pragma unroll
            for (int nt = 0; nt < 4; nt++)
#pragma unroll
                for (int reg = 0; reg < 4; reg++)
                    sc[nt][reg] = (nt * 16 + c > w * 16 + g * 4 + reg) ? -INFINITY : sc[nt][reg];
        }
        // ---- online softmax ----
        float al[4];
#pragma unroll
        for (int reg = 0; reg < 4; reg++) {
            float mx = fmaxf(fmaxf(sc[0][reg], sc[1][reg]), fmaxf(sc[2][reg], sc[3][reg]));
            mx = fmaxf(mx, __shfl_xor(mx, 1));
            mx = fmaxf(mx, __shfl_xor(mx, 2));
            mx = fmaxf(mx, __shfl_xor(mx, 4));
            mx = fmaxf(mx, __shfl_xor(mx, 8));
            const float mn = fmaxf(m[reg], mx);
            const float a  = __expf(m[reg] - mn);
            m[reg] = mn; al[reg] = a;
            float ps = 0.0f;
#pragma unroll
            for (int nt = 0; nt < 4; nt++) {
                float p = __expf(sc[nt][reg] - mn);
                sc[nt][reg] = p; ps += p;
            }
            ps += __shfl_xor(ps, 1); ps += __shfl_xor(ps, 2);
            ps += __shfl_xor(ps, 4); ps += __shfl_xor(ps, 8);
            lsum[reg] = lsum[reg] * a + ps;
        }
#pragma unroll
        for (int f = 0; f < 4; f++)
#pragma unroll
            for (int reg = 0; reg < 4; reg++)
                O[f][reg] *= al[reg];
        // ---- P: C-layout -> LDS -> A-layout (per-wave slice) ----
#pragma unroll
        for (int nt = 0; nt < 4; nt++)
#pragma unroll
            for (int reg = 0; reg < 4; reg++)
                Pl[w][g * 4 + reg][nt * 16 + c] = f2bf(sc[nt][reg]);
        __syncthreads();
        short8 pa0 = *(const short8*)&Pl[w][c][g * 8];
        short8 pa1 = *(const short8*)&Pl[w][c][32 + g * 8];
        // ---- PV ----
#pragma unroll
        for (int nt = 0; nt < 4; nt++) {
            const unsigned short* vp = Vh + ((long)(nt * 16 + c)) * S_ + t0 + g * 8;
            short8 vb0 = *(const short8*)vp;
            short8 vb1 = *(const short8*)(vp + 32);
            O[nt] = __builtin_amdgcn_mfma_f32_16x16x32_bf16(pa0, vb0, O[nt], 0, 0, 0);
            O[nt] = __builtin_amdgcn_mfma_f32_16x16x32_bf16(pa1, vb1, O[nt], 0, 0, 0);
        }
    }

    // ---- epilogue: bf16 ctx ----
#pragma unroll
    for (int reg = 0; reg < 4; reg++) {
        const float rl = 1.0f / lsum[reg];
        unsigned short* op = ctxb + ((long)(b * S_) + qrow0 + g * 4 + reg) * D_ + h * DH_ + c;
#pragma unroll
        for (int f = 0; f < 4; f++)
            op[f * 16] = f2bf(O[f][reg] * rl);
    }
}

// ---------------------------------------------------------------------------
extern "C" void kernel_launch(void* const* d_in, const int* in_sizes, int n_in,
                              void* d_out, int out_size, void* d_ws, size_t ws_size,
                              hipStream_t stream)
{
    const float* x    = (const float*)d_in[0];
    const float* pk   = (const float*)d_in[1];
    const float* pv   = (const float*)d_in[2];
    const float* Wqkv = (const float*)d_in[3];
    const float* bqkv = (const float*)d_in[4];
    const float* Wk   = (const float*)d_in[5];
    const float* bk   = (const float*)d_in[6];
    const float* Wv   = (const float*)d_in[7];
    const float* bv   = (const float*)d_in[8];
    const float* Wo   = (const float*)d_in[9];
    const float* bo   = (const float*)d_in[10];

    float* out   = (float*)d_out;                      // [B,S,D]
    float* k_col = out + (long)B_ * S_ * D_;           // [B,H,S,DH]
    float* v_col = k_col + (long)B_ * H_ * S_ * DH_;   // [B,H,S,DH]

    const int M = B_ * S_;   // 4096
    const long MD = (long)M * D_;

    unsigned short* xb    = (unsigned short*)d_ws;     // [M,D]
    unsigned short* Wqkvb = xb + MD;                   // [3D,D]
    unsigned short* Wkb   = Wqkvb + 3L * D_ * D_;      // [D,D]
    unsigned short* Wvb   = Wkb + (long)D_ * D_;
    unsigned short* Wob   = Wvb + (long)D_ * D_;
    unsigned short* qkvb  = Wob + (long)D_ * D_;       // [M,3D]
    unsigned short* Kb    = qkvb + 3 * MD;             // [B,H,S,DH]
    unsigned short* Vtb   = Kb + MD;                   // [B,H,DH,S]
    unsigned short* ctxb  = Vtb + MD;                  // [M,D]

    dim3 blk(256);

    // fp32 -> bf16 converts
    cvt_bf16<<<dim3((int)(MD / 2048)), blk, 0, stream>>>(x, xb, MD);
    cvt_bf16<<<dim3((int)(3L * D_ * D_ / 2048)), blk, 0, stream>>>(Wqkv, Wqkvb, 3L * D_ * D_);
    cvt_bf16<<<dim3((int)((long)D_ * D_ / 2048)), blk, 0, stream>>>(Wk, Wkb, (long)D_ * D_);
    cvt_bf16<<<dim3((int)((long)D_ * D_ / 2048)), blk, 0, stream>>>(Wv, Wvb, (long)D_ * D_);
    cvt_bf16<<<dim3((int)((long)D_ * D_ / 2048)), blk, 0, stream>>>(Wo, Wob, (long)D_ * D_);

    // 1) qkv = x @ Wqkv.T + bqkv -> bf16 [M,3D]
    gemm_bf16<<<dim3(3 * D_ / 128, M / 128), blk, 0, stream>>>(xb, Wqkvb, bqkv, qkvb, M, 3 * D_, D_, 2);
    // 2) packed bf16 K + transposed bf16 V
    prepass<<<dim3(B_ * H_ * (S_ / 64)), blk, 0, stream>>>(qkvb, Kb, Vtb);
    // 3) k_col / v_col head-split fp32
    gemm_bf16<<<dim3(D_ / 128, M / 128), blk, 0, stream>>>(xb, Wkb, bk, k_col, M, D_, D_, 1);
    gemm_bf16<<<dim3(D_ / 128, M / 128), blk, 0, stream>>>(xb, Wvb, bv, v_col, M, D_, D_, 1);
    // 4) attention -> bf16 ctx
    attn_mfma<<<dim3(B_ * H_ * (S_ / 64)), blk, 0, stream>>>(qkvb, Kb, Vtb, pk, pv, ctxb);
    // 5) out = ctx @ Wo.T + bo -> fp32
    gemm_bf16<<<dim3(D_ / 128, M / 128), blk, 0, stream>>>(ctxb, Wob, bo, out, M, D_, D_, 0);
}